// Round 11
// baseline (98.107 us; speedup 1.0000x reference)
//
#include <hip/hip_runtime.h>
#include <hip/hip_bf16.h>

typedef unsigned short u16;
typedef __attribute__((ext_vector_type(8))) short bf16x8;
typedef __attribute__((ext_vector_type(4))) float f32x4;
typedef __attribute__((ext_vector_type(16))) float f32x16;
typedef __attribute__((ext_vector_type(4))) int i32x4;
typedef __attribute__((ext_vector_type(2))) unsigned int u32x2;

constexpr int SEN  = 128;
constexpr int CIN  = 270;
constexpr int NOUT = 984;
constexpr int XROW = 256;          // bytes per xT row (16 slots x 16B)
constexpr int XTB  = 130 * XROW;   // 33,280 B per buffer
constexpr int WEBP = 256;          // bf16 word-table row pitch (bytes)
constexpr size_t WS_BASE = 90112 + 61440 + 491520;          // WB+SE3+SR3
constexpr size_t WS_NEED = WS_BASE + 50000ull * WEBP;       // +12.8 MB

__device__ inline float ftanh(float x) {
    float e = __expf(2.0f * x);
    return 1.0f - 2.0f * __builtin_amdgcn_rcpf(e + 1.0f);
}
__device__ inline unsigned pk2(float x, float y) {
    union { __hip_bfloat162 h; unsigned u; } v;
    v.h = __float22bfloat162_rn(float2{x, y});
    return v.u;
}
__device__ __forceinline__ void gload_lds16(const void* g, void* l) {
    __builtin_amdgcn_global_load_lds(
        (const __attribute__((address_space(1))) void*)g,
        (__attribute__((address_space(3))) void*)l, 16, 0, 0);
}

// ---------------------------------------------------------------------------
// prep_all: WB[kg(44)][dc(128)][8] bf16 (K-major weights, g = kg*8+j,
// tap = g/112 (<3), ch = g-112*tap, zero for ch>=110 or g>=336), SE3, SR3,
// loc path, and the bf16 word table weB[50000][128] (cols 100..127 = 0).
// blocks [0,176): WB  [176,236): SE3  [236,716): SR3  [716,2764): loc
//        [2764, 15264): weB (launched only when ws fits)
// ---------------------------------------------------------------------------
__global__ void prep_all(const float* __restrict__ w, const float* __restrict__ ee,
                         const float* __restrict__ re, const int* __restrict__ loc,
                         const int* __restrict__ lmark, const float* __restrict__ we,
                         u16* __restrict__ WB, float* __restrict__ SE3,
                         float* __restrict__ SR3, u16* __restrict__ weB,
                         float* __restrict__ out) {
    const int b = blockIdx.x, tid = threadIdx.x;
    if (b < 176) {
        int i = b * 256 + tid;                // < 45056 = 44*128*8
        int kg = i >> 10;                     // 0..43
        int dc = (i >> 3) & 127;
        int j  = i & 7;
        int g  = kg * 8 + j;
        int tap = (g >= 112) + (g >= 224);
        int ch  = g - 112 * tap;
        float v = (g < 336 && ch < 110) ? w[(dc * CIN + ch) * 3 + tap] : 0.0f;
        union { __hip_bfloat16 h; u16 u; } cv;
        cv.h = __float2bfloat16(v);
        WB[i] = cv.u;
    } else if (b < 236) {
        int i = (b - 176) * 256 + tid;        // < 15360
        int k = i % 3, rest = i / 3;
        int dc = rest & 127, e = rest >> 7;
        float a = 0.f;
        for (int j = 0; j < 32; ++j)
            a += w[(dc * CIN + 110 + j) * 3 + k] * ee[e * 32 + j];
        SE3[i] = a;
    } else if (b < 716) {
        int i = (b - 236) * 256 + tid;        // < 122880
        int k = i % 3, rest = i / 3;
        int dc = rest & 127, rr = rest >> 7;
        int r = rr % 40, j = rr / 40;
        float a = 0.f;
        for (int d = 0; d < 16; ++d)
            a += w[(dc * CIN + 142 + j * 16 + d) * 3 + k] * re[r * 16 + d];
        SR3[i] = a;
    } else if (b < 2764) {
        int li = b - 716;                     // 0..2047, two samples per block
        int s = li * 2 + (tid >> 7);
        int d = tid & 127;
        if (d < 100) {
            const int* L = loc + (size_t)s * 16;
            float* o = out + (size_t)s * NOUT + 384;
#pragma unroll
            for (int i = 0; i < 4; ++i)
                o[i * 100 + d] = ftanh(we[(size_t)L[i] * 100 + d]);
            int mk = lmark[s];
            float acc = 0.f;
            for (int j = 0; j < mk; ++j)
                acc += we[(size_t)L[4 + j] * 100 + d];
            o[4 * 100 + d] = ftanh(acc / (float)mk);
            o[5 * 100 + d] = ftanh(we[(size_t)L[4 + mk] * 100 + d]);
        }
    } else {
        // bf16 word table: i over u32 pairs, 50000*64 entries
        size_t i = (size_t)(b - 2764) * 256 + tid;   // < 3,200,000
        int v  = (int)(i >> 6), cp = (int)(i & 63);
        int c0 = cp * 2;
        float x0 = (c0     < 100) ? we[(size_t)v * 100 + c0]     : 0.f;
        float x1 = (c0 + 1 < 100) ? we[(size_t)v * 100 + c0 + 1] : 0.f;
        ((unsigned*)weB)[(size_t)v * 64 + cp] = pk2(x0, x1);
    }
}

// ---------------------------------------------------------------------------
// Main: 512 blocks x 512 thr (8 waves), 2 blocks/CU. Swapped GEMM:
// D[tok][dc] = xT(tokens,K from LDS) x WB(K,dc from L2), 32x32x16 MFMA.
// Wave w: token-slice q = w>>1 (32 tokens), dc-half dch = w&1 (2 x 32 dc).
// Masked max-pool is in-lane over the 16 token-rows + 1 shfl; partials
// combine through a small LDS buffer. Staging identical to R10 (async
// global_load_lds one sample ahead; double-buffered xT; 2 barriers/sample).
// ---------------------------------------------------------------------------
template <bool GLD>
__global__ __launch_bounds__(512, 4)
void conv_pool(const int* __restrict__ inp, const int* __restrict__ pos1,
               const int* __restrict__ pos2, const int* __restrict__ subtype,
               const int* __restrict__ argRole,
               const float* __restrict__ maskL, const float* __restrict__ maskM,
               const float* __restrict__ maskR,
               const float* __restrict__ we, const float* __restrict__ pe,
               const float* __restrict__ cb,
               const u16* __restrict__ WB, const float* __restrict__ SE3,
               const float* __restrict__ SR3, const u16* __restrict__ weB,
               float* __restrict__ out)
{
    __shared__ __align__(16) char xT[2][XTB];   // 66,560 B
    __shared__ float sc[2][3 * 128];            //  3,072 B
    __shared__ float msk[2][3 * 128];           //  3,072 B
    __shared__ float part[12 * 128];            //  6,144 B

    const int tid  = threadIdx.x;
    const int lane = tid & 63;
    const int wid  = tid >> 6;
    const int l31  = lane & 31;
    const int hi   = lane >> 5;
    const int q    = wid >> 1;        // token slice [q*32, q*32+32)
    const int dch  = wid & 1;         // dc half

    // zero both xT buffers once (rows 0/129 stay zero)
    {
        i32x4 z = {0, 0, 0, 0};
        i32x4* pz = (i32x4*)xT;
#pragma unroll
        for (int i = 0; i < 9; ++i) {
            int o = tid + i * 512;
            if (o < 2 * XTB / 16) pz[o] = z;
        }
    }
    __syncthreads();

    // ---- A (xT) byte-offsets per K-step (sample-invariant, 22 VGPRs) ----
    int addrA[22];
#pragma unroll
    for (int ks = 0; ks < 22; ++ks) {
        int tap = (ks >= 7) + (ks >= 14);
        int c0  = ks * 2 - 14 * tap;          // logical slot base
        int row = q * 32 + l31 + tap;
        int slot = (c0 + hi) ^ (row & 15);
        addrA[ks] = row * XROW + (slot << 4);
    }

    // ---- W (weights) per-lane base: kg = 2*ks + hi, dc = dch*64 + l31 ----
    const char* wpBase = (const char*)WB + hi * 2048 + ((dch * 64 + l31) << 4);

    const int sbase = blockIdx.x * 8;

    // ---- persistent small-stage registers ----
    float sk0 = 0.f, sk1 = 0.f, sk2 = 0.f;
    float cbv = (tid < 128) ? cb[tid] : 0.f;
    float pp[10];
#pragma unroll
    for (int i = 0; i < 10; ++i) pp[i] = 0.f;

    auto issueGather = [&](int s, char* xb, float* mb) {
#pragma unroll
        for (int qq = 0; qq < 4; ++qq) {
            const int j   = (wid << 2) + qq;           // 0..31
            const int tok = (j << 2) + (lane >> 4);    // 4 tokens per instr
            const int idx = inp[s * SEN + tok];
            const int e   = (lane & 15) ^ ((tok + 1) & 15);  // pre-swizzled src
            const char* src = (const char*)weB + (size_t)idx * WEBP + (e << 4);
            gload_lds16(src, xb + XROW + (j << 10));
        }
        if (wid == 4) {   // masks
            const char* gL = (const char*)(maskL + (size_t)s * SEN);
            const char* gM = (const char*)(maskM + (size_t)s * SEN);
            const char* gR = (const char*)(maskR + (size_t)s * SEN);
            const char* s1 = (lane < 32) ? gL + (lane << 4)
                                         : gM + ((lane - 32) << 4);
            gload_lds16(s1, (char*)mb);
            if (lane < 32)
                gload_lds16(gR + (lane << 4), (char*)mb + 1024);
        }
    };

    auto smallLoad = [&](int s) {
        if (tid < 128) {
            int sub = subtype[s];
            i32x4 a0 = *(const i32x4*)(argRole + s * 8);
            i32x4 a1 = *(const i32x4*)(argRole + s * 8 + 4);
            int arr[8] = {a0[0], a0[1], a0[2], a0[3], a1[0], a1[1], a1[2], a1[3]};
            const float* bb = SE3 + (sub * 128 + tid) * 3;
            sk0 = bb[0]; sk1 = bb[1]; sk2 = bb[2];
#pragma unroll
            for (int j = 0; j < 8; ++j) {
                const float* rb = SR3 + ((j * 40 + arr[j]) * 128 + tid) * 3;
                sk0 += rb[0]; sk1 += rb[1]; sk2 += rb[2];
            }
        } else if (tid < 256) {
            int t = tid - 128;
            int p1 = pos1[s * SEN + t], p2 = pos2[s * SEN + t];
#pragma unroll
            for (int i = 0; i < 5; ++i) {
                pp[i]     = pe[p1 * 5 + i];
                pp[5 + i] = pe[p2 * 5 + i];
            }
        }
    };

    auto smallCommit = [&](int s, char* xb, float* scb, float* mb) {
        if (tid < 128) {
            scb[tid]       = sk0 + sk1 + sk2 + cbv;
            scb[128 + tid] = sk0;
            scb[256 + tid] = sk2;
        } else if (tid < 256) {
            int t = tid - 128, row = t + 1, rx = row & 15;
            u32x2 wa = { pk2(pp[0], pp[1]), pk2(pp[2], pp[3]) };   // ch 100..103
            *(u32x2*)(xb + row * XROW + ((12 ^ rx) << 4) + 8) = wa;
            union { bf16x8 v; unsigned u[4]; } wb;                  // ch 104..111
            wb.u[0] = pk2(pp[4], pp[5]); wb.u[1] = pk2(pp[6], pp[7]);
            wb.u[2] = pk2(pp[8], pp[9]); wb.u[3] = 0;
            *(bf16x8*)(xb + row * XROW + ((13 ^ rx) << 4)) = wb.v;
        }
        if constexpr (!GLD) {
#pragma unroll
            for (int jj = 0; jj < 7; ++jj) {
                int qf = tid + jj * 512;
                if (qf < 3200) {
                    int tok = qf / 25;
                    int e   = qf - tok * 25;
                    int idx = inp[s * SEN + tok];
                    f32x4 v = *(const f32x4*)(we + (size_t)idx * 100 + e * 4);
                    int row  = tok + 1;
                    int phys = (e >> 1) ^ (row & 15);
                    u32x2 wv = { pk2(v[0], v[1]), pk2(v[2], v[3]) };
                    *(u32x2*)(xb + row * XROW + (phys << 4) + (e & 1) * 8) = wv;
                }
            }
            if (tid >= 256 && tid < 352) {
                int i = tid - 256;
                int m = i >> 5, j4 = i & 31;
                const float* msrc = (m == 0) ? maskL : (m == 1) ? maskM : maskR;
                *(f32x4*)(mb + m * 128 + j4 * 4) =
                    *(const f32x4*)(msrc + (size_t)s * SEN + j4 * 4);
            }
        }
    };

    // ---- prologue ----
    smallLoad(sbase);
    if constexpr (GLD) issueGather(sbase, xT[0], msk[0]);
    __syncthreads();
    smallCommit(sbase, xT[0], sc[0], msk[0]);
    __syncthreads();

    for (int it = 0; it < 8; ++it) {
        const int s   = sbase + it;
        const int cur = it & 1;
        const char* xc = xT[cur];

        if (it < 7) {
            if constexpr (GLD) issueGather(s + 1, xT[cur ^ 1], msk[cur ^ 1]);
            smallLoad(s + 1);
        }

        // launder W pointer (forbid cross-sample CSE)
        const char* wp = wpBase;
        asm volatile("" : "+v"(wp));

        // ---- GEMM: D[32tok][2x32dc], 22 K-steps ----
        f32x16 acc0, acc1;
#pragma unroll
        for (int r = 0; r < 16; ++r) { acc0[r] = 0.f; acc1[r] = 0.f; }

#pragma unroll
        for (int ks = 0; ks < 22; ++ks) {
            bf16x8 xa = *(const bf16x8*)(xc + addrA[ks]);
            bf16x8 w0 = *(const bf16x8*)(wp + ks * 4096);
            bf16x8 w1 = *(const bf16x8*)(wp + ks * 4096 + 512);
            acc0 = __builtin_amdgcn_mfma_f32_32x32x16_bf16(xa, w0, acc0, 0, 0, 0);
            acc1 = __builtin_amdgcn_mfma_f32_32x32x16_bf16(xa, w1, acc1, 0, 0, 0);
        }

        // ---- epilogue: in-lane masked max over token rows ----
        const float* scc = sc[cur];
        const float* mc  = msk[cur];
        const int dc0 = dch * 64 + l31;
        const int dc1 = dc0 + 32;
        const float sall0 = scc[dc0], sall1 = scc[dc1];

        float v0[16], v1[16];
#pragma unroll
        for (int r = 0; r < 16; ++r) {
            v0[r] = acc0[r] + sall0;
            v1[r] = acc1[r] + sall1;
        }
        if (q == 0 && lane < 32) {           // token 0 = row 0 (r=0, hi=0)
            v0[0] -= scc[128 + dc0];
            v1[0] -= scc[128 + dc1];
        }
        if (q == 3 && lane >= 32) {          // token 127 = row 31 (r=15, hi=1)
            v0[15] -= scc[256 + dc0];
            v1[15] -= scc[256 + dc1];
        }

#pragma unroll
        for (int m = 0; m < 3; ++m) {
            float pm0 = -1e30f, pm1 = -1e30f;
#pragma unroll
            for (int g = 0; g < 4; ++g) {
                f32x4 mk = *(const f32x4*)(mc + m * 128 + q * 32 + g * 8 + hi * 4);
#pragma unroll
                for (int j = 0; j < 4; ++j) {
                    int r = g * 4 + j;
                    pm0 = fmaxf(pm0, __builtin_fmaf(v0[r], mk[j], 1.f));
                    pm1 = fmaxf(pm1, __builtin_fmaf(v1[r], mk[j], 1.f));
                }
            }
            pm0 = fmaxf(pm0, __shfl_xor(pm0, 32));
            pm1 = fmaxf(pm1, __shfl_xor(pm1, 32));
            if (lane < 32) {
                part[(m * 4 + q) * 128 + dc0] = pm0;
                part[(m * 4 + q) * 128 + dc1] = pm1;
            }
        }

        __syncthreads();   // part visible; gather(s+1) drained

        // ---- combine partials -> tanh -> out ----
        if (tid < 384) {
            int m = tid >> 7, dc = tid & 127;
            const float* pb = part + m * 4 * 128 + dc;
            float v = fmaxf(fmaxf(pb[0], pb[128]), fmaxf(pb[256], pb[384]));
            out[(size_t)s * NOUT + m * 128 + dc] = ftanh(v - 1.f);
        }
        if (it < 7) smallCommit(s + 1, xT[cur ^ 1], sc[cur ^ 1], msk[cur ^ 1]);
        __syncthreads();
    }
}

// ---------------------------------------------------------------------------
extern "C" void kernel_launch(void* const* d_in, const int* in_sizes, int n_in,
                              void* d_out, int out_size, void* d_ws, size_t ws_size,
                              hipStream_t stream) {
    const int*   inp     = (const int*)d_in[0];
    const int*   pos1    = (const int*)d_in[1];
    const int*   pos2    = (const int*)d_in[2];
    const int*   loc     = (const int*)d_in[3];
    const int*   lmark   = (const int*)d_in[4];
    const int*   subtype = (const int*)d_in[5];
    const int*   argRole = (const int*)d_in[6];
    const float* maskL   = (const float*)d_in[7];
    const float* maskM   = (const float*)d_in[8];
    const float* maskR   = (const float*)d_in[9];
    const float* we      = (const float*)d_in[10];
    const float* pe      = (const float*)d_in[11];
    const float* ee      = (const float*)d_in[12];
    const float* re      = (const float*)d_in[13];
    const float* cw      = (const float*)d_in[14];
    const float* cb      = (const float*)d_in[15];
    float* out = (float*)d_out;

    char* ws = (char*)d_ws;
    u16*   WB  = (u16*)ws;                         // 90,112 B
    float* SE3 = (float*)(ws + 90112);             // 61,440 B
    float* SR3 = (float*)(ws + 90112 + 61440);     // 491,520 B
    u16*   weB = (u16*)(ws + WS_BASE);             // 12,800,000 B (GLD mode)

    const bool gld = (ws_size >= WS_NEED);
    const int prepGrid = gld ? 15264 : 2764;

    hipLaunchKernelGGL(prep_all, dim3(prepGrid), dim3(256), 0, stream,
                       cw, ee, re, loc, lmark, we, WB, SE3, SR3, weB, out);
    if (gld) {
        hipLaunchKernelGGL((conv_pool<true>), dim3(512), dim3(512), 0, stream,
                           inp, pos1, pos2, subtype, argRole, maskL, maskM, maskR,
                           we, pe, cb, WB, SE3, SR3, weB, out);
    } else {
        hipLaunchKernelGGL((conv_pool<false>), dim3(512), dim3(512), 0, stream,
                           inp, pos1, pos2, subtype, argRole, maskL, maskM, maskR,
                           we, pe, cb, WB, SE3, SR3, weB, out);
    }
}

// Round 12
// 93.925 us; speedup vs baseline: 1.0445x; 1.0445x over previous
//
#include <hip/hip_runtime.h>
#include <hip/hip_bf16.h>

typedef unsigned short u16;
typedef __attribute__((ext_vector_type(8))) short bf16x8;
typedef __attribute__((ext_vector_type(4))) float f32x4;
typedef __attribute__((ext_vector_type(16))) float f32x16;
typedef __attribute__((ext_vector_type(4))) int i32x4;
typedef __attribute__((ext_vector_type(2))) unsigned int u32x2;

constexpr int SEN  = 128;
constexpr int CIN  = 270;
constexpr int NOUT = 984;
constexpr int XROW = 256;          // bytes per xT row (16 slots x 16B)
constexpr int XTB  = 130 * XROW;   // 33,280 B per buffer
constexpr int WEBP = 256;          // bf16 word-table row pitch (bytes)
constexpr size_t WS_BASE = 90112 + 61440 + 491520;          // WB+SE3+SR3
constexpr size_t WS_NEED = WS_BASE + 50000ull * WEBP;       // +12.8 MB

__device__ inline float ftanh(float x) {
    float e = __expf(2.0f * x);
    return 1.0f - 2.0f * __builtin_amdgcn_rcpf(e + 1.0f);
}
__device__ inline unsigned pk2(float x, float y) {
    union { __hip_bfloat162 h; unsigned u; } v;
    v.h = __float22bfloat162_rn(float2{x, y});
    return v.u;
}
__device__ __forceinline__ void gload_lds16(const void* g, void* l) {
    __builtin_amdgcn_global_load_lds(
        (const __attribute__((address_space(1))) void*)g,
        (__attribute__((address_space(3))) void*)l, 16, 0, 0);
}

// ---------------------------------------------------------------------------
// prep_all: WB[kg(44)][dc(128)][8] bf16 (K-major weights), SE3, SR3, loc path,
// and the bf16 word table weB[50000][128] (cols 100..127 = 0).
// blocks [0,176): WB  [176,236): SE3  [236,716): SR3  [716,2764): loc
//        [2764, 15264): weB (launched only when ws fits)
// ---------------------------------------------------------------------------
__global__ void prep_all(const float* __restrict__ w, const float* __restrict__ ee,
                         const float* __restrict__ re, const int* __restrict__ loc,
                         const int* __restrict__ lmark, const float* __restrict__ we,
                         u16* __restrict__ WB, float* __restrict__ SE3,
                         float* __restrict__ SR3, u16* __restrict__ weB,
                         float* __restrict__ out) {
    const int b = blockIdx.x, tid = threadIdx.x;
    if (b < 176) {
        int i = b * 256 + tid;                // < 45056 = 44*128*8
        int kg = i >> 10;                     // 0..43
        int dc = (i >> 3) & 127;
        int j  = i & 7;
        int g  = kg * 8 + j;
        int tap = (g >= 112) + (g >= 224);
        int ch  = g - 112 * tap;
        float v = (g < 336 && ch < 110) ? w[(dc * CIN + ch) * 3 + tap] : 0.0f;
        union { __hip_bfloat16 h; u16 u; } cv;
        cv.h = __float2bfloat16(v);
        WB[i] = cv.u;
    } else if (b < 236) {
        int i = (b - 176) * 256 + tid;        // < 15360
        int k = i % 3, rest = i / 3;
        int dc = rest & 127, e = rest >> 7;
        float a = 0.f;
        for (int j = 0; j < 32; ++j)
            a += w[(dc * CIN + 110 + j) * 3 + k] * ee[e * 32 + j];
        SE3[i] = a;
    } else if (b < 716) {
        int i = (b - 236) * 256 + tid;        // < 122880
        int k = i % 3, rest = i / 3;
        int dc = rest & 127, rr = rest >> 7;
        int r = rr % 40, j = rr / 40;
        float a = 0.f;
        for (int d = 0; d < 16; ++d)
            a += w[(dc * CIN + 142 + j * 16 + d) * 3 + k] * re[r * 16 + d];
        SR3[i] = a;
    } else if (b < 2764) {
        int li = b - 716;                     // 0..2047, two samples per block
        int s = li * 2 + (tid >> 7);
        int d = tid & 127;
        if (d < 100) {
            const int* L = loc + (size_t)s * 16;
            float* o = out + (size_t)s * NOUT + 384;
#pragma unroll
            for (int i = 0; i < 4; ++i)
                o[i * 100 + d] = ftanh(we[(size_t)L[i] * 100 + d]);
            int mk = lmark[s];
            float acc = 0.f;
            for (int j = 0; j < mk; ++j)
                acc += we[(size_t)L[4 + j] * 100 + d];
            o[4 * 100 + d] = ftanh(acc / (float)mk);
            o[5 * 100 + d] = ftanh(we[(size_t)L[4 + mk] * 100 + d]);
        }
    } else {
        // bf16 word table: i over u32 pairs, 50000*64 entries
        size_t i = (size_t)(b - 2764) * 256 + tid;   // < 3,200,000
        int v  = (int)(i >> 6), cp = (int)(i & 63);
        int c0 = cp * 2;
        float x0 = (c0     < 100) ? we[(size_t)v * 100 + c0]     : 0.f;
        float x1 = (c0 + 1 < 100) ? we[(size_t)v * 100 + c0 + 1] : 0.f;
        ((unsigned*)weB)[(size_t)v * 64 + cp] = pk2(x0, x1);
    }
}

// ---------------------------------------------------------------------------
// Main: 512 blocks x 512 thr (8 waves), 2 blocks/CU. Swapped GEMM:
// D[tok][dc] = xT(LDS) x WB(L2), 32x32x16 MFMA. Wave w = (tokHalf h2 = w&1,
// dcSlice ds = w>>1): 64 tok x 32 dc via TWO MFMAs sharing ONE W load per
// K-step (halves W L2 traffic vs R11). Masked pool in-lane + 1 shfl;
// partials (2 per dc) combine via small LDS. Staging identical to R11.
// ---------------------------------------------------------------------------
template <bool GLD>
__global__ __launch_bounds__(512, 4)
void conv_pool(const int* __restrict__ inp, const int* __restrict__ pos1,
               const int* __restrict__ pos2, const int* __restrict__ subtype,
               const int* __restrict__ argRole,
               const float* __restrict__ maskL, const float* __restrict__ maskM,
               const float* __restrict__ maskR,
               const float* __restrict__ we, const float* __restrict__ pe,
               const float* __restrict__ cb,
               const u16* __restrict__ WB, const float* __restrict__ SE3,
               const float* __restrict__ SR3, const u16* __restrict__ weB,
               float* __restrict__ out)
{
    __shared__ __align__(16) char xT[2][XTB];   // 66,560 B
    __shared__ float sc[2][3 * 128];            //  3,072 B
    __shared__ float msk[2][3 * 128];           //  3,072 B
    __shared__ float part[6 * 128];             //  3,072 B

    const int tid  = threadIdx.x;
    const int lane = tid & 63;
    const int wid  = tid >> 6;
    const int l31  = lane & 31;
    const int hi   = lane >> 5;
    const int h2   = wid & 1;         // token half: [h2*64, h2*64+64)
    const int ds   = wid >> 1;        // dc slice:   [ds*32, ds*32+32)

    // zero both xT buffers once (rows 0/129 stay zero)
    {
        i32x4 z = {0, 0, 0, 0};
        i32x4* pz = (i32x4*)xT;
#pragma unroll
        for (int i = 0; i < 9; ++i) {
            int o = tid + i * 512;
            if (o < 2 * XTB / 16) pz[o] = z;
        }
    }
    __syncthreads();

    // ---- A (xT) byte-offsets per K-step for MFMA tile 0 (tokens h2*64+0..31);
    // tile 1 (tokens +32) is addrA[ks] + 32*XROW (same swizzle: row&15 inv.)
    int addrA[22];
#pragma unroll
    for (int ks = 0; ks < 22; ++ks) {
        int tap = (ks >= 7) + (ks >= 14);
        int c0  = ks * 2 - 14 * tap;
        int row = h2 * 64 + l31 + tap;
        int slot = (c0 + hi) ^ (row & 15);
        addrA[ks] = row * XROW + (slot << 4);
    }

    // ---- W per-lane base: kg = 2*ks + hi, dc = ds*32 + l31 ----
    const char* wpBase = (const char*)WB + hi * 2048 + ((ds * 32 + l31) << 4);

    const int sbase = blockIdx.x * 8;

    // ---- persistent small-stage registers ----
    float sk0 = 0.f, sk1 = 0.f, sk2 = 0.f;
    float cbv = (tid < 128) ? cb[tid] : 0.f;
    float pp[10];
#pragma unroll
    for (int i = 0; i < 10; ++i) pp[i] = 0.f;

    auto issueGather = [&](int s, char* xb, float* mb) {
#pragma unroll
        for (int qq = 0; qq < 4; ++qq) {
            const int j   = (wid << 2) + qq;           // 0..31
            const int tok = (j << 2) + (lane >> 4);    // 4 tokens per instr
            const int idx = inp[s * SEN + tok];
            const int e   = (lane & 15) ^ ((tok + 1) & 15);  // pre-swizzled src
            const char* src = (const char*)weB + (size_t)idx * WEBP + (e << 4);
            gload_lds16(src, xb + XROW + (j << 10));
        }
        if (wid == 4) {   // masks
            const char* gL = (const char*)(maskL + (size_t)s * SEN);
            const char* gM = (const char*)(maskM + (size_t)s * SEN);
            const char* gR = (const char*)(maskR + (size_t)s * SEN);
            const char* s1 = (lane < 32) ? gL + (lane << 4)
                                         : gM + ((lane - 32) << 4);
            gload_lds16(s1, (char*)mb);
            if (lane < 32)
                gload_lds16(gR + (lane << 4), (char*)mb + 1024);
        }
    };

    auto smallLoad = [&](int s) {
        if (tid < 128) {
            int sub = subtype[s];
            i32x4 a0 = *(const i32x4*)(argRole + s * 8);
            i32x4 a1 = *(const i32x4*)(argRole + s * 8 + 4);
            int arr[8] = {a0[0], a0[1], a0[2], a0[3], a1[0], a1[1], a1[2], a1[3]};
            const float* bb = SE3 + (sub * 128 + tid) * 3;
            sk0 = bb[0]; sk1 = bb[1]; sk2 = bb[2];
#pragma unroll
            for (int j = 0; j < 8; ++j) {
                const float* rb = SR3 + ((j * 40 + arr[j]) * 128 + tid) * 3;
                sk0 += rb[0]; sk1 += rb[1]; sk2 += rb[2];
            }
        } else if (tid < 256) {
            int t = tid - 128;
            int p1 = pos1[s * SEN + t], p2 = pos2[s * SEN + t];
#pragma unroll
            for (int i = 0; i < 5; ++i) {
                pp[i]     = pe[p1 * 5 + i];
                pp[5 + i] = pe[p2 * 5 + i];
            }
        }
    };

    auto smallCommit = [&](int s, char* xb, float* scb, float* mb) {
        if (tid < 128) {
            scb[tid]       = sk0 + sk1 + sk2 + cbv;
            scb[128 + tid] = sk0;
            scb[256 + tid] = sk2;
        } else if (tid < 256) {
            int t = tid - 128, row = t + 1, rx = row & 15;
            u32x2 wa = { pk2(pp[0], pp[1]), pk2(pp[2], pp[3]) };   // ch 100..103
            *(u32x2*)(xb + row * XROW + ((12 ^ rx) << 4) + 8) = wa;
            union { bf16x8 v; unsigned u[4]; } wb;                  // ch 104..111
            wb.u[0] = pk2(pp[4], pp[5]); wb.u[1] = pk2(pp[6], pp[7]);
            wb.u[2] = pk2(pp[8], pp[9]); wb.u[3] = 0;
            *(bf16x8*)(xb + row * XROW + ((13 ^ rx) << 4)) = wb.v;
        }
        if constexpr (!GLD) {
#pragma unroll
            for (int jj = 0; jj < 7; ++jj) {
                int qf = tid + jj * 512;
                if (qf < 3200) {
                    int tok = qf / 25;
                    int e   = qf - tok * 25;
                    int idx = inp[s * SEN + tok];
                    f32x4 v = *(const f32x4*)(we + (size_t)idx * 100 + e * 4);
                    int row  = tok + 1;
                    int phys = (e >> 1) ^ (row & 15);
                    u32x2 wv = { pk2(v[0], v[1]), pk2(v[2], v[3]) };
                    *(u32x2*)(xb + row * XROW + (phys << 4) + (e & 1) * 8) = wv;
                }
            }
            if (tid >= 256 && tid < 352) {
                int i = tid - 256;
                int m = i >> 5, j4 = i & 31;
                const float* msrc = (m == 0) ? maskL : (m == 1) ? maskM : maskR;
                *(f32x4*)(mb + m * 128 + j4 * 4) =
                    *(const f32x4*)(msrc + (size_t)s * SEN + j4 * 4);
            }
        }
    };

    // ---- prologue ----
    smallLoad(sbase);
    if constexpr (GLD) issueGather(sbase, xT[0], msk[0]);
    __syncthreads();
    smallCommit(sbase, xT[0], sc[0], msk[0]);
    __syncthreads();

    for (int it = 0; it < 8; ++it) {
        const int s   = sbase + it;
        const int cur = it & 1;
        const char* xc = xT[cur];

        if (it < 7) {
            if constexpr (GLD) issueGather(s + 1, xT[cur ^ 1], msk[cur ^ 1]);
            smallLoad(s + 1);
        }

        // launder W pointer (forbid cross-sample CSE)
        const char* wp = wpBase;
        asm volatile("" : "+v"(wp));

        // ---- GEMM: D[2x32tok][32dc], 22 K-steps, ONE W load per step ----
        f32x16 acc0, acc1;
#pragma unroll
        for (int r = 0; r < 16; ++r) { acc0[r] = 0.f; acc1[r] = 0.f; }

#pragma unroll
        for (int ks = 0; ks < 22; ++ks) {
            bf16x8 xa0 = *(const bf16x8*)(xc + addrA[ks]);
            bf16x8 xa1 = *(const bf16x8*)(xc + addrA[ks] + 32 * XROW);
            bf16x8 w0  = *(const bf16x8*)(wp + ks * 4096);
            acc0 = __builtin_amdgcn_mfma_f32_32x32x16_bf16(xa0, w0, acc0, 0, 0, 0);
            acc1 = __builtin_amdgcn_mfma_f32_32x32x16_bf16(xa1, w0, acc1, 0, 0, 0);
        }

        // ---- epilogue: in-lane masked max over token rows ----
        const float* scc = sc[cur];
        const float* mc  = msk[cur];
        const int dc = ds * 32 + l31;
        const float sall = scc[dc];

        float v0[16], v1[16];
#pragma unroll
        for (int r = 0; r < 16; ++r) {
            v0[r] = acc0[r] + sall;
            v1[r] = acc1[r] + sall;
        }
        if (h2 == 0 && lane < 32)   // token 0 = tile0, row 0 (r=0, hi=0)
            v0[0] -= scc[128 + dc];
        if (h2 == 1 && lane >= 32)  // token 127 = tile1, row 31 (r=15, hi=1)
            v1[15] -= scc[256 + dc];

#pragma unroll
        for (int m = 0; m < 3; ++m) {
            float pm = -1e30f;
#pragma unroll
            for (int g = 0; g < 4; ++g) {
                f32x4 mk0 = *(const f32x4*)(mc + m * 128 + h2 * 64 + g * 8 + hi * 4);
                f32x4 mk1 = *(const f32x4*)(mc + m * 128 + h2 * 64 + 32 + g * 8 + hi * 4);
#pragma unroll
                for (int j = 0; j < 4; ++j) {
                    int r = g * 4 + j;
                    pm = fmaxf(pm, __builtin_fmaf(v0[r], mk0[j], 1.f));
                    pm = fmaxf(pm, __builtin_fmaf(v1[r], mk1[j], 1.f));
                }
            }
            pm = fmaxf(pm, __shfl_xor(pm, 32));
            if (lane < 32)
                part[(m * 2 + h2) * 128 + dc] = pm;
        }

        __syncthreads();   // part visible; gather(s+1) drained

        // ---- combine partials -> tanh -> out ----
        if (tid < 384) {
            int m = tid >> 7, dcx = tid & 127;
            const float* pb = part + m * 2 * 128 + dcx;
            float v = fmaxf(pb[0], pb[128]);
            out[(size_t)s * NOUT + m * 128 + dcx] = ftanh(v - 1.f);
        }
        if (it < 7) smallCommit(s + 1, xT[cur ^ 1], sc[cur ^ 1], msk[cur ^ 1]);
        __syncthreads();
    }
}

// ---------------------------------------------------------------------------
extern "C" void kernel_launch(void* const* d_in, const int* in_sizes, int n_in,
                              void* d_out, int out_size, void* d_ws, size_t ws_size,
                              hipStream_t stream) {
    const int*   inp     = (const int*)d_in[0];
    const int*   pos1    = (const int*)d_in[1];
    const int*   pos2    = (const int*)d_in[2];
    const int*   loc     = (const int*)d_in[3];
    const int*   lmark   = (const int*)d_in[4];
    const int*   subtype = (const int*)d_in[5];
    const int*   argRole = (const int*)d_in[6];
    const float* maskL   = (const float*)d_in[7];
    const float* maskM   = (const float*)d_in[8];
    const float* maskR   = (const float*)d_in[9];
    const float* we      = (const float*)d_in[10];
    const float* pe      = (const float*)d_in[11];
    const float* ee      = (const float*)d_in[12];
    const float* re      = (const float*)d_in[13];
    const float* cw      = (const float*)d_in[14];
    const float* cb      = (const float*)d_in[15];
    float* out = (float*)d_out;

    char* ws = (char*)d_ws;
    u16*   WB  = (u16*)ws;                         // 90,112 B
    float* SE3 = (float*)(ws + 90112);             // 61,440 B
    float* SR3 = (float*)(ws + 90112 + 61440);     // 491,520 B
    u16*   weB = (u16*)(ws + WS_BASE);             // 12,800,000 B (GLD mode)

    const bool gld = (ws_size >= WS_NEED);
    const int prepGrid = gld ? 15264 : 2764;

    hipLaunchKernelGGL(prep_all, dim3(prepGrid), dim3(256), 0, stream,
                       cw, ee, re, loc, lmark, we, WB, SE3, SR3, weB, out);
    if (gld) {
        hipLaunchKernelGGL((conv_pool<true>), dim3(512), dim3(512), 0, stream,
                           inp, pos1, pos2, subtype, argRole, maskL, maskM, maskR,
                           we, pe, cb, WB, SE3, SR3, weB, out);
    } else {
        hipLaunchKernelGGL((conv_pool<false>), dim3(512), dim3(512), 0, stream,
                           inp, pos1, pos2, subtype, argRole, maskL, maskM, maskR,
                           we, pe, cb, WB, SE3, SR3, weB, out);
    }
}